// Round 2
// baseline (3352.977 us; speedup 1.0000x reference)
//
#include <hip/hip_runtime.h>

// Problem constants (from setup_inputs): B=4, L=32, C=16, H=192, W=192
#define BB 4
#define LL 32
#define CC 16
#define HH 192
#define WW 192
#define HW (HH * WW)            // 36864
#define CHW (CC * HW)           // 589824
#define IMG_ELEMS ((size_t)BB * LL * CHW)      // 75,497,472
#define FLW_ELEMS ((size_t)BB * LL * 2 * HW)   // 9,437,184

// Location rule: when step s runs, slice u's latest copy lives at dst(q) with
// q = min(s/2, msb(u)); q==0 -> original input.
// Image dsts:  dst(1)=buf0, dst(2)=out, dst(4)=buf0, dst(8)=out, dst(16)=out
// Flow dsts:   dst(1)=fb0,  dst(2)=fb1, dst(4)=fb0,  dst(8)=fb1
__device__ __forceinline__ const float* sel3(int u, int shalf,
                                             const float* pin,
                                             const float* pa,   // q in {1,4}
                                             const float* pb) { // q in {2,8,16}
  int q = (u > 0) ? (1 << (31 - __builtin_clz((unsigned)u))) : 0;
  q = q < shalf ? q : shalf;
  if (q == 0) return pin;
  return (q == 1 || q == 4) ? pa : pb;
}

__global__ __launch_bounds__(256) void pscan_step(
    const float* __restrict__ img_in, const float* __restrict__ img_b0,
    const float* __restrict__ img_out_r,
    const float* __restrict__ flow_in, const float* __restrict__ flow_b0,
    const float* __restrict__ flow_b1,
    float* __restrict__ img_dst, float* __restrict__ flow_dst,
    int s, int write_flow) {
  // Match the numpy f32 reference rounding-for-rounding: no FMA contraction.
  // (The x-wrap seam is discontinuous; 1-ULP drift flips samples across it.)
#pragma clang fp contract(off)
  const int b = blockIdx.z;
  const int t = blockIdx.y + s;      // t in [s, L)
  const int u = t - s;               // source slice
  const int tile = blockIdx.x;       // 144 tiles: 3 across (64 wide) x 48 down (4 tall)
  const int w = (tile % 3) * 64 + threadIdx.x;
  const int h = (tile / 3) * 4 + threadIdx.y;
  const int shalf = s >> 1;

  const float* fcur = sel3(t, shalf, flow_in, flow_b0, flow_b1);
  const float* fprv = sel3(u, shalf, flow_in, flow_b0, flow_b1);
  const float* icur = sel3(t, shalf, img_in, img_b0, img_out_r);
  const float* iprv = sel3(u, shalf, img_in, img_b0, img_out_r);

  const int p = h * WW + w;

  // current flow at (b,t,:,h,w)
  const size_t fcbase = ((size_t)(b * LL + t) * 2) * HW;
  const float fcx = fcur[fcbase + p];
  const float fcy = fcur[fcbase + HW + p];

  // warp grid (pixel-center base grid + flow), wrap x into [-1,1)
  // gx = (w+0.5)*(2/W) - 1; fx = gx + flow_x  (exact reference op order)
  const float gx = (w + 0.5f) * (2.0f / WW) - 1.0f;
  const float gy = (h + 0.5f) * (2.0f / HH) - 1.0f;
  float fx = gx + fcx;
  float fy = gy + fcy;
  // np.remainder(fx+1, 2) - 1
  float r = fmodf(fx + 1.0f, 2.0f);
  if (r < 0.0f) r += 2.0f;
  fx = r - 1.0f;

  // bilinear, align_corners=False, zeros padding
  const float ix = (fx + 1.0f) * 0.5f * WW - 0.5f;
  const float iy = (fy + 1.0f) * 0.5f * HH - 0.5f;
  const float x0f = floorf(ix), y0f = floorf(iy);
  const float wx1 = ix - x0f, wy1 = iy - y0f;
  const float wx0 = 1.0f - wx1, wy0 = 1.0f - wy1;
  const int x0 = (int)x0f, y0 = (int)y0f;
  const int x1 = x0 + 1, y1 = y0 + 1;
  const bool vx0 = (x0 >= 0) & (x0 < WW), vx1 = (x1 >= 0) & (x1 < WW);
  const bool vy0 = (y0 >= 0) & (y0 < HH), vy1 = (y1 >= 0) & (y1 < HH);
  const int cx0 = min(max(x0, 0), WW - 1), cx1 = min(max(x1, 0), WW - 1);
  const int cy0 = min(max(y0, 0), HH - 1), cy1 = min(max(y1, 0), HH - 1);
  // weight * valid is exact (valid is 0.0 or 1.0), so this matches
  // (v*valid)*w of the reference rounding-for-rounding.
  const float w00 = wy0 * wx0 * ((vy0 && vx0) ? 1.0f : 0.0f);
  const float w01 = wy0 * wx1 * ((vy0 && vx1) ? 1.0f : 0.0f);
  const float w10 = wy1 * wx0 * ((vy1 && vx0) ? 1.0f : 0.0f);
  const float w11 = wy1 * wx1 * ((vy1 && vx1) ? 1.0f : 0.0f);
  const int i00 = cy0 * WW + cx0, i01 = cy0 * WW + cx1;
  const int i10 = cy1 * WW + cx0, i11 = cy1 * WW + cx1;

  if (write_flow) {
    const float* fp0 = fprv + ((size_t)(b * LL + u) * 2) * HW;
    const float* fp1 = fp0 + HW;
    const float s0 = w00 * fp0[i00] + w01 * fp0[i01] + w10 * fp0[i10] + w11 * fp0[i11];
    const float s1 = w00 * fp1[i00] + w01 * fp1[i01] + w10 * fp1[i10] + w11 * fp1[i11];
    flow_dst[fcbase + p] = fcx + s0;
    flow_dst[fcbase + HW + p] = fcy + s1;
  }

  const float* ip = iprv + (size_t)(b * LL + u) * CHW;
  const float* ic = icur + (size_t)(b * LL + t) * CHW;
  float* od = img_dst + (size_t)(b * LL + t) * CHW;
#pragma unroll 4
  for (int c = 0; c < CC; ++c) {
    const float* pl = ip + c * HW;
    const float sv = w00 * pl[i00] + w01 * pl[i01] + w10 * pl[i10] + w11 * pl[i11];
    od[c * HW + p] = ic[c * HW + p] + sv;
  }
}

// Final locations after all steps: t=0 -> in, t=1 -> buf0, t in [2,4) -> out,
// t in [4,8) -> buf0, t in [8,32) -> out. Copy the 6 missing slices into out.
__global__ __launch_bounds__(256) void pscan_fixup(
    const float* __restrict__ img_in, const float* __restrict__ img_b0,
    float* __restrict__ img_out) {
  const int per_slice4 = (int)(BB * CHW / 4);  // float4s per copied t-slice (all b)
  int tid = blockIdx.x * blockDim.x + threadIdx.x;
  int j = tid / per_slice4;
  if (j >= 6) return;
  int e = tid % per_slice4;
  const int t = (j == 0) ? 0 : (j == 1 ? 1 : j + 2);  // 0,1,4,5,6,7
  const float* src = (j == 0) ? img_in : img_b0;
  const int b = e / (CHW / 4);
  const int rr = e % (CHW / 4);
  const size_t base = (size_t)(b * LL + t) * CHW;
  const float4* s4 = (const float4*)(src + base) + rr;
  float4* d4 = (float4*)(img_out + base) + rr;
  *d4 = *s4;
}

extern "C" void kernel_launch(void* const* d_in, const int* in_sizes, int n_in,
                              void* d_out, int out_size, void* d_ws, size_t ws_size,
                              hipStream_t stream) {
  const float* flow_in = (const float*)d_in[0];
  const float* img_in  = (const float*)d_in[1];
  float* img_out = (float*)d_out;

  float* img_b0  = (float*)d_ws;                 // 301,989,888 bytes
  float* flow_b0 = img_b0 + IMG_ELEMS;           // 37,748,736 bytes
  float* flow_b1 = flow_b0 + FLW_ELEMS;          // 37,748,736 bytes
  // total ws needed: 377,487,360 bytes

  const dim3 blk(64, 4, 1);
  const int steps[5] = {1, 2, 4, 8, 16};
  for (int i = 0; i < 5; ++i) {
    const int s = steps[i];
    const dim3 grd(144, LL - s, BB);
    float* idst = (s == 1 || s == 4) ? img_b0 : img_out;
    float* fdst = (s == 1 || s == 4) ? flow_b0 : flow_b1;  // unused at s=16
    pscan_step<<<grd, blk, 0, stream>>>(img_in, img_b0, img_out,
                                        flow_in, flow_b0, flow_b1,
                                        idst, fdst, s, (s < 16) ? 1 : 0);
  }
  const int total4 = 6 * BB * CHW / 4;  // 3,538,944 float4 copies
  pscan_fixup<<<(total4 + 255) / 256, 256, 0, stream>>>(img_in, img_b0, img_out);
}